// Round 1
// baseline (235.527 us; speedup 1.0000x reference)
//
#include <hip/hip_runtime.h>

// Involution: B=16, C=256, H=W=56, mid=64, GROUPS=16, GROUP_SIZE=16, K=3 (KK=9)
// Inputs (all fp32): x(16,256,56,56), w1(64,256), bn_gamma(64), bn_beta(64),
//                    bn_mean(64), bn_var(64), w2(144,64), b2(144)
// Output fp32: (16,256,56,56)

#define Cn    256
#define MID   64
#define Hn    56
#define Wn    56
#define HW    3136            // 56*56
#define Bn    16
#define NPIX  (Bn * HW)       // 50176
#define CHW   (Cn * HW)
#define NKK   9
#define NG    16
#define GSZ   16
#define BN_EPS 1e-5f

// ---------------------------------------------------------------------------
// prep: w1f[c*64+o] = w1[o*256+c] * scale[o];  bias1[o] = beta[o]-mean[o]*scale[o]
// ---------------------------------------------------------------------------
__global__ __launch_bounds__(256) void prep_kernel(
    const float* __restrict__ w1,
    const float* __restrict__ gamma,
    const float* __restrict__ beta,
    const float* __restrict__ mean,
    const float* __restrict__ var,
    float* __restrict__ w1f,
    float* __restrict__ bias1) {
  int idx = blockIdx.x * 256 + threadIdx.x;
  if (idx < MID * Cn) {
    int c = idx >> 6;
    int o = idx & 63;
    float scale = gamma[o] / sqrtf(var[o] + BN_EPS);
    w1f[idx] = w1[o * Cn + c] * scale;
  } else if (idx < MID * Cn + MID) {
    int o = idx - MID * Cn;
    float scale = gamma[o] / sqrtf(var[o] + BN_EPS);
    bias1[o] = beta[o] - mean[o] * scale;
  }
}

// ---------------------------------------------------------------------------
// conv1: t[o][gp] = relu(bias1[o] + sum_c x[b,c,hw] * w1f[c][o])
// thread = 1 pixel, 32 outputs (blockIdx.y selects o-chunk)
// ---------------------------------------------------------------------------
__global__ __launch_bounds__(256) void conv1_kernel(
    const float* __restrict__ x,
    const float* __restrict__ w1f,
    const float* __restrict__ bias1,
    float* __restrict__ t) {
  int gp = blockIdx.x * 256 + threadIdx.x;   // 0..50175, exact (196*256)
  int o0 = blockIdx.y * 32;
  int b  = gp / HW;
  int hw = gp - b * HW;
  const float* xp = x + (size_t)b * CHW + hw;

  float acc[32];
#pragma unroll
  for (int j = 0; j < 32; ++j) acc[j] = bias1[o0 + j];

  for (int c = 0; c < Cn; ++c) {
    float xv = xp[(size_t)c * HW];
    const float4* wr = (const float4*)(w1f + c * MID + o0);
#pragma unroll
    for (int q = 0; q < 8; ++q) {
      float4 w4 = wr[q];
      acc[4 * q + 0] = fmaf(xv, w4.x, acc[4 * q + 0]);
      acc[4 * q + 1] = fmaf(xv, w4.y, acc[4 * q + 1]);
      acc[4 * q + 2] = fmaf(xv, w4.z, acc[4 * q + 2]);
      acc[4 * q + 3] = fmaf(xv, w4.w, acc[4 * q + 3]);
    }
  }

#pragma unroll
  for (int j = 0; j < 32; ++j)
    t[(size_t)(o0 + j) * NPIX + gp] = fmaxf(acc[j], 0.0f);
}

// ---------------------------------------------------------------------------
// conv2 + involution fused: thread = 1 pixel, 4 groups (blockIdx.y selects)
//   wk[kk] = b2[g*9+kk] + sum_o t[o][gp] * w2[(g*9+kk)*64+o]
//   out[b, g*16+cc, hw] = sum_kk wk[kk] * x[b, g*16+cc, h+kk/3-1, w+kk%3-1]
// ---------------------------------------------------------------------------
__global__ __launch_bounds__(256) void conv2_inv_kernel(
    const float* __restrict__ x,
    const float* __restrict__ t,
    const float* __restrict__ w2,
    const float* __restrict__ b2,
    float* __restrict__ out) {
  int gp = blockIdx.x * 256 + threadIdx.x;
  int g0 = blockIdx.y * 4;
  int b  = gp / HW;
  int hw = gp - b * HW;
  int h  = hw / Wn;
  int w  = hw - h * Wn;

  // load this pixel's 64 conv1 activations (coalesced: lane = pixel)
  float treg[MID];
  const float* tp = t + gp;
#pragma unroll
  for (int o = 0; o < MID; ++o) treg[o] = tp[(size_t)o * NPIX];

  const float* xb = x + (size_t)b * CHW + hw;  // + c*HW + (di*56+dj) later

  for (int gi = 0; gi < 4; ++gi) {
    int g = g0 + gi;

    // --- conv2: 9 per-pixel kernel weights for this group ---
    float wk[NKK];
#pragma unroll
    for (int kk = 0; kk < NKK; ++kk) {
      int o2 = g * NKK + kk;
      float s = b2[o2];
      const float4* w2r = (const float4*)(w2 + o2 * MID);  // contiguous row of 64
#pragma unroll
      for (int q = 0; q < 16; ++q) {
        float4 w4 = w2r[q];
        s = fmaf(treg[4 * q + 0], w4.x, s);
        s = fmaf(treg[4 * q + 1], w4.y, s);
        s = fmaf(treg[4 * q + 2], w4.z, s);
        s = fmaf(treg[4 * q + 3], w4.w, s);
      }
      wk[kk] = s;
    }

    // --- involution: 16 channels of this group, 9 taps ---
    float oacc[GSZ];
#pragma unroll
    for (int cc = 0; cc < GSZ; ++cc) oacc[cc] = 0.0f;

#pragma unroll
    for (int kk = 0; kk < NKK; ++kk) {
      int di = kk / 3 - 1;
      int dj = kk % 3 - 1;
      int h2 = h + di;
      int w2v = w + dj;
      if (h2 >= 0 && h2 < Hn && w2v >= 0 && w2v < Wn) {
        const float* xr = xb + (size_t)(g * GSZ) * HW + di * Wn + dj;
        float wv = wk[kk];
#pragma unroll
        for (int cc = 0; cc < GSZ; ++cc)
          oacc[cc] = fmaf(wv, xr[(size_t)cc * HW], oacc[cc]);
      }
    }

    float* op = out + (size_t)b * CHW + (size_t)(g * GSZ) * HW + hw;
#pragma unroll
    for (int cc = 0; cc < GSZ; ++cc)
      op[(size_t)cc * HW] = oacc[cc];
  }
}

// ---------------------------------------------------------------------------
extern "C" void kernel_launch(void* const* d_in, const int* in_sizes, int n_in,
                              void* d_out, int out_size, void* d_ws, size_t ws_size,
                              hipStream_t stream) {
  const float* x     = (const float*)d_in[0];
  const float* w1    = (const float*)d_in[1];
  const float* gamma = (const float*)d_in[2];
  const float* beta  = (const float*)d_in[3];
  const float* mean  = (const float*)d_in[4];
  const float* var   = (const float*)d_in[5];
  const float* w2    = (const float*)d_in[6];
  const float* b2    = (const float*)d_in[7];
  float* out = (float*)d_out;

  // workspace layout: t (64 x 50176 fp32 = 12.85 MB) | w1f (64 KB) | bias1 (256 B)
  char* ws = (char*)d_ws;
  float* t     = (float*)ws;
  float* w1f   = (float*)(ws + (size_t)MID * NPIX * 4);
  float* bias1 = (float*)(ws + (size_t)MID * NPIX * 4 + (size_t)MID * Cn * 4);

  prep_kernel<<<(MID * Cn + MID + 255) / 256, 256, 0, stream>>>(
      w1, gamma, beta, mean, var, w1f, bias1);
  conv1_kernel<<<dim3(NPIX / 256, 2), 256, 0, stream>>>(x, w1f, bias1, t);
  conv2_inv_kernel<<<dim3(NPIX / 256, 4), 256, 0, stream>>>(x, t, w2, b2, out);
}